// Round 5
// baseline (525.303 us; speedup 1.0000x reference)
//
#include <hip/hip_runtime.h>
#include <hip/hip_bf16.h>

// Mamba2 forward, MI355X (gfx950).
// casts -> GEMM1 (BK=64 global_load_lds MFMA, XCD-swizzled, bf16 out)
// -> conv+silu+dt (fused) -> SSD passA (local Y + chunk states, parallel)
// -> SSD passB (sequential chunk-state scan) -> SSD passC (inter-chunk Y)
// -> gate+RMSNorm -> GEMM2 (64x128 tiles).
// States (67MB bf16): d_out scratch (33.5MB) + ws region shared with cast bufs.

typedef __attribute__((ext_vector_type(8))) short bf16x8;
typedef __attribute__((ext_vector_type(4))) float f32x4;

static constexpr int B_ = 4;
static constexpr int L_ = 2048;
static constexpr int NROWS = B_ * L_;
static constexpr int DMODEL = 1024;
static constexpr int DINNER = 2048;
static constexpr int NH = 32;
static constexpr int DSTATE = 128;
static constexpr int CONVDIM = DINNER + 2 * DSTATE;          // 2304
static constexpr int DINPROJ = 2 * DINNER + 2 * DSTATE + NH; // 4384
static constexpr int Q_ = 64;
static constexpr int NCHUNK = L_ / Q_;                        // 32

__device__ __forceinline__ unsigned pk_bf16(float a, float b) {
  unsigned ua = __builtin_bit_cast(unsigned, a);
  unsigned ub = __builtin_bit_cast(unsigned, b);
  ua = (ua + 0x7FFFu + ((ua >> 16) & 1u)) >> 16;
  ub = (ub + 0x7FFFu + ((ub >> 16) & 1u)) >> 16;
  return (ua & 0xFFFFu) | (ub << 16);
}
__device__ __forceinline__ unsigned short bf16_of(float a) {
  unsigned ua = __builtin_bit_cast(unsigned, a);
  return (unsigned short)((ua + 0x7FFFu + ((ua >> 16) & 1u)) >> 16);
}
__device__ __forceinline__ float f_of_bf16(unsigned short s) {
  return __builtin_bit_cast(float, (unsigned)s << 16);
}
__device__ __forceinline__ unsigned short* state_slot(unsigned short* lo,
                                                      unsigned short* hi,
                                                      int bh, int c) {
  int i = bh * NCHUNK + c;
  return (i < 2048) ? lo + (size_t)i * 8192 : hi + (size_t)(i - 2048) * 8192;
}

__global__ __launch_bounds__(256) void cast4_kernel(const float* __restrict__ in,
                                                    unsigned short* __restrict__ out) {
  int i = blockIdx.x * 256 + threadIdx.x;
  float4 v = ((const float4*)in)[i];
  ((uint2*)out)[i] = make_uint2(pk_bf16(v.x, v.y), pk_bf16(v.z, v.w));
}

// C[M][N] = A[M][K] * Bw[N][K]^T, bf16. MT x 128 tile, BK=64, 4 waves.
// global_load_lds width-16 staging; 1D grid with XCD swizzle:
// xcd = bid&7, by = xcd*per_xcd + (bid>>3)%per_xcd, bx = (bid>>3)/per_xcd.
// NOTE: GEMM1 reads B rows up to n0+127 >= N (OOB rows land in adjacent ws
// memory -- harmless; epilogue bounds-checks gcol<N).
template <int MT, bool C_BF16>
__global__ __launch_bounds__(256) void gemm_lds_kernel(
    const unsigned short* __restrict__ A, const unsigned short* __restrict__ Bw,
    void* __restrict__ Cp, int M, int N, int K, int lda, int ldb, int ldc,
    int per_xcd) {
  constexpr int IB = MT / 32;                 // 16-row blocks per wave (rows)
  __shared__ unsigned short sA[MT * 64];
  __shared__ unsigned short sB[128 * 64];
  const int tid = threadIdx.x;
  const int w = tid >> 6;
  const int lane = tid & 63;
  const int bid = blockIdx.x;
  const int xcd = bid & 7;
  const int t = bid >> 3;
  const int by = xcd * per_xcd + (t % per_xcd);
  const int bx = t / per_xcd;
  const int m0 = by * MT;
  const int n0 = bx * 128;
  const int wm = (w >> 1) * (MT / 2);
  const int wn = (w & 1) * 64;
  const int lr = lane >> 3;                   // 8 rows/issue
  const int lc8 = (lane & 7) * 8;             // 8 bf16 = 16B per lane

  f32x4 acc[IB][4];
#pragma unroll
  for (int i = 0; i < IB; ++i)
#pragma unroll
    for (int j = 0; j < 4; ++j) acc[i][j] = f32x4{0.f, 0.f, 0.f, 0.f};

  auto ldsA = (__attribute__((address_space(3))) unsigned short*)sA;
  auto ldsB = (__attribute__((address_space(3))) unsigned short*)sB;

  for (int k0 = 0; k0 < K; k0 += 64) {
#pragma unroll
    for (int s = 0; s < IB; ++s) {            // A: MT rows
      int row = w * (MT / 4) + s * 8;
      __builtin_amdgcn_global_load_lds(
          (const __attribute__((address_space(1))) void*)(A + (size_t)(m0 + row + lr) * lda + k0 + lc8),
          (__attribute__((address_space(3))) void*)(ldsA + row * 64), 16, 0, 0);
    }
#pragma unroll
    for (int s = 0; s < 4; ++s) {             // B: 128 rows
      int row = w * 32 + s * 8;
      __builtin_amdgcn_global_load_lds(
          (const __attribute__((address_space(1))) void*)(Bw + (size_t)(n0 + row + lr) * ldb + k0 + lc8),
          (__attribute__((address_space(3))) void*)(ldsB + row * 64), 16, 0, 0);
    }
    __syncthreads();
    const int r15 = lane & 15;
#pragma unroll
    for (int kb = 0; kb < 2; ++kb) {
      const int kcol = kb * 32 + (lane >> 4) * 8;
      bf16x8 af[IB], bfr[4];
#pragma unroll
      for (int i = 0; i < IB; ++i)
        af[i] = *(const bf16x8*)(sA + (wm + i * 16 + r15) * 64 + kcol);
#pragma unroll
      for (int j = 0; j < 4; ++j)
        bfr[j] = *(const bf16x8*)(sB + (wn + j * 16 + r15) * 64 + kcol);
#pragma unroll
      for (int i = 0; i < IB; ++i)
#pragma unroll
        for (int j = 0; j < 4; ++j)
          acc[i][j] = __builtin_amdgcn_mfma_f32_16x16x32_bf16(af[i], bfr[j], acc[i][j], 0, 0, 0);
    }
    __syncthreads();
  }

  const int rr = ((lane >> 4)) * 4;
  const int cc = lane & 15;
#pragma unroll
  for (int i = 0; i < IB; ++i) {
#pragma unroll
    for (int j = 0; j < 4; ++j) {
      int gcol = n0 + wn + j * 16 + cc;
      if (gcol < N) {
#pragma unroll
        for (int r = 0; r < 4; ++r) {
          size_t grow = (size_t)(m0 + wm + i * 16 + rr + r);
          if constexpr (C_BF16)
            ((unsigned short*)Cp)[grow * ldc + gcol] = bf16_of(acc[i][j][r]);
          else
            ((float*)Cp)[grow * ldc + gcol] = acc[i][j][r];
        }
      }
    }
  }
}

// conv(D_CONV=4) + bias + SiLU (bf16 in/out) with dt=softplus fused into block x==0.
__global__ __launch_bounds__(256) void conv_dt_kernel(const unsigned short* __restrict__ zx,
                                                      const float* __restrict__ conv_w,
                                                      const float* __restrict__ conv_b,
                                                      const float* __restrict__ dt_bias,
                                                      unsigned short* __restrict__ xbc,
                                                      float* __restrict__ dtv) {
  int c = blockIdx.x * 256 + threadIdx.x;  // 9*256 == CONVDIM
  int row = blockIdx.y;
  int l = row & (L_ - 1);
  float acc = conv_b[c];
#pragma unroll
  for (int k = 0; k < 4; ++k) {
    int ll = l + k - 3;
    if (ll >= 0)
      acc = fmaf(f_of_bf16(zx[(size_t)(row + k - 3) * DINPROJ + DINNER + c]),
                 conv_w[c * 4 + k], acc);
  }
  acc = acc / (1.f + __expf(-acc));
  xbc[(size_t)row * CONVDIM + c] = bf16_of(acc);
  if (blockIdx.x == 0 && threadIdx.x < NH) {
    int hh = threadIdx.x;
    float x = f_of_bf16(zx[(size_t)row * DINPROJ + DINNER + CONVDIM + hh]) + dt_bias[hh];
    dtv[(size_t)row * NH + hh] = (x > 20.f) ? x : log1pf(__expf(x));
  }
}

// ---- SSD pass A: per (b,chunk,head). Local Y (+D*x) in place over x-region;
// chunk state S_c -> state slot (bf16 [p][n], 64x128).
__global__ __launch_bounds__(256) void ssd_passA(unsigned short* __restrict__ xbc,
                                                 const float* __restrict__ dtv,
                                                 const float* __restrict__ A_log,
                                                 const float* __restrict__ Dvec,
                                                 unsigned short* __restrict__ st_lo,
                                                 unsigned short* __restrict__ st_hi) {
  const int bid = blockIdx.x;          // ((b*32 + c)*32 + h)
  const int h = bid & 31;
  const int c = (bid >> 5) & 31;
  const int b = bid >> 10;
  const int bh = b * 32 + h;
  const int tid = threadIdx.x;
  const int w = tid >> 6;
  const int lane = tid & 63;
  const int quad = lane >> 4;
  const int c15 = lane & 15;

  __shared__ unsigned short sXt[64 * 72];   // X^T [p][t]
  __shared__ unsigned short sBq[64 * 136];  // B [s][n]; S~ alias stride 72
  __shared__ unsigned short sCB[128 * 72];  // C [t][n] stride 136 / BtT [n][s] stride 72
  __shared__ float sdt[64], scs[64], sg[64];

  const float A = -__expf(A_log[h]);
  const float Dh = Dvec[h];
  const int r0 = b * L_ + c * Q_;

  if (w == 0) {
    float v = dtv[(size_t)(r0 + lane) * NH + h];
    sdt[lane] = v;
    float s = v;
#pragma unroll
    for (int off = 1; off < 64; off <<= 1) {
      float t = __shfl_up(s, off, 64);
      if (lane >= off) s += t;
    }
    scs[lane] = s;
    float T = __shfl(s, 63, 64);
    sg[lane] = __expf(A * (T - s)) * v;
  }
  for (int e = tid; e < 512; e += 256) {   // Xt transpose
    int t = e & 63, pb = e >> 6;
    uint4 v = *(const uint4*)&xbc[(size_t)(r0 + t) * CONVDIM + h * 64 + pb * 8];
    const unsigned short* sv = (const unsigned short*)&v;
#pragma unroll
    for (int j = 0; j < 8; ++j) sXt[(pb * 8 + j) * 72 + t] = sv[j];
  }
  for (int e = tid; e < 1024; e += 256) {  // B, C coalesced
    int s = e >> 4, ch = e & 15;
    size_t roff = (size_t)(r0 + s) * CONVDIM + DINNER;
    *(uint4*)&sBq[s * 136 + ch * 8] = *(const uint4*)&xbc[roff + ch * 8];
    *(uint4*)&sCB[s * 136 + ch * 8] = *(const uint4*)&xbc[roff + DSTATE + ch * 8];
  }
  __syncthreads();  // B1

  const int wt = w >> 1, wx = w & 1;
  f32x4 sacc[2][2];
#pragma unroll
  for (int i = 0; i < 2; ++i)
#pragma unroll
    for (int j = 0; j < 2; ++j) sacc[i][j] = f32x4{0.f, 0.f, 0.f, 0.f};
#pragma unroll
  for (int kk = 0; kk < 4; ++kk) {
    int k8 = quad * 8 + kk * 32;
    bf16x8 a0 = *(const bf16x8*)&sCB[(wt * 32 + c15) * 136 + k8];
    bf16x8 a1 = *(const bf16x8*)&sCB[(wt * 32 + 16 + c15) * 136 + k8];
    bf16x8 b0 = *(const bf16x8*)&sBq[(wx * 32 + c15) * 136 + k8];
    bf16x8 b1 = *(const bf16x8*)&sBq[(wx * 32 + 16 + c15) * 136 + k8];
    sacc[0][0] = __builtin_amdgcn_mfma_f32_16x16x32_bf16(a0, b0, sacc[0][0], 0, 0, 0);
    sacc[0][1] = __builtin_amdgcn_mfma_f32_16x16x32_bf16(a0, b1, sacc[0][1], 0, 0, 0);
    sacc[1][0] = __builtin_amdgcn_mfma_f32_16x16x32_bf16(a1, b0, sacc[1][0], 0, 0, 0);
    sacc[1][1] = __builtin_amdgcn_mfma_f32_16x16x32_bf16(a1, b1, sacc[1][1], 0, 0, 0);
  }
  __syncthreads();  // B2

#pragma unroll
  for (int i = 0; i < 2; ++i)
#pragma unroll
    for (int j = 0; j < 2; ++j) {
      int scol = wx * 32 + j * 16 + c15;
      float css = scs[scol], dts = sdt[scol];
#pragma unroll
      for (int r = 0; r < 4; ++r) {
        int trow = wt * 32 + i * 16 + quad * 4 + r;
        float v = (scol <= trow) ? sacc[i][j][r] * __expf(A * (scs[trow] - css)) * dts : 0.f;
        sBq[trow * 72 + scol] = bf16_of(v);
      }
    }
  for (int e = tid; e < 1024; e += 256) {  // BtT[n][s] = B[s][n]*g_s
    int s = e & 63, nb = e >> 6;
    uint4 v = *(const uint4*)&xbc[(size_t)(r0 + s) * CONVDIM + DINNER + nb * 8];
    float g = sg[s];
    const unsigned short* sv = (const unsigned short*)&v;
#pragma unroll
    for (int j = 0; j < 8; ++j)
      sCB[(nb * 8 + j) * 72 + s] = bf16_of(f_of_bf16(sv[j]) * g);
  }
  __syncthreads();  // B3

  unsigned short* sS = sBq;
  f32x4 yacc[2][2];
#pragma unroll
  for (int i = 0; i < 2; ++i)
#pragma unroll
    for (int j = 0; j < 2; ++j) yacc[i][j] = f32x4{0.f, 0.f, 0.f, 0.f};
#pragma unroll
  for (int kk = 0; kk < 2; ++kk) {
    int k8 = quad * 8 + kk * 32;
    bf16x8 a0 = *(const bf16x8*)&sS[(wt * 32 + c15) * 72 + k8];
    bf16x8 a1 = *(const bf16x8*)&sS[(wt * 32 + 16 + c15) * 72 + k8];
    bf16x8 b0 = *(const bf16x8*)&sXt[(wx * 32 + c15) * 72 + k8];
    bf16x8 b1 = *(const bf16x8*)&sXt[(wx * 32 + 16 + c15) * 72 + k8];
    yacc[0][0] = __builtin_amdgcn_mfma_f32_16x16x32_bf16(a0, b0, yacc[0][0], 0, 0, 0);
    yacc[0][1] = __builtin_amdgcn_mfma_f32_16x16x32_bf16(a0, b1, yacc[0][1], 0, 0, 0);
    yacc[1][0] = __builtin_amdgcn_mfma_f32_16x16x32_bf16(a1, b0, yacc[1][0], 0, 0, 0);
    yacc[1][1] = __builtin_amdgcn_mfma_f32_16x16x32_bf16(a1, b1, yacc[1][1], 0, 0, 0);
  }
#pragma unroll
  for (int i = 0; i < 2; ++i)
#pragma unroll
    for (int j = 0; j < 2; ++j) {
      int p = wx * 32 + j * 16 + c15;
#pragma unroll
      for (int r = 0; r < 4; ++r) {
        int t = wt * 32 + i * 16 + quad * 4 + r;
        float xv = f_of_bf16(sXt[p * 72 + t]);
        xbc[(size_t)(r0 + t) * CONVDIM + h * 64 + p] = bf16_of(yacc[i][j][r] + Dh * xv);
      }
    }

  f32x4 hacc[2][4];
#pragma unroll
  for (int i = 0; i < 2; ++i)
#pragma unroll
    for (int j = 0; j < 4; ++j) hacc[i][j] = f32x4{0.f, 0.f, 0.f, 0.f};
  const int wp = w >> 1, wn = w & 1;
#pragma unroll
  for (int kk = 0; kk < 2; ++kk) {
    int k8 = quad * 8 + kk * 32;
    bf16x8 a0 = *(const bf16x8*)&sXt[(wp * 32 + c15) * 72 + k8];
    bf16x8 a1 = *(const bf16x8*)&sXt[(wp * 32 + 16 + c15) * 72 + k8];
    bf16x8 bfr[4];
#pragma unroll
    for (int j = 0; j < 4; ++j)
      bfr[j] = *(const bf16x8*)&sCB[(wn * 64 + j * 16 + c15) * 72 + k8];
#pragma unroll
    for (int j = 0; j < 4; ++j) {
      hacc[0][j] = __builtin_amdgcn_mfma_f32_16x16x32_bf16(a0, bfr[j], hacc[0][j], 0, 0, 0);
      hacc[1][j] = __builtin_amdgcn_mfma_f32_16x16x32_bf16(a1, bfr[j], hacc[1][j], 0, 0, 0);
    }
  }
  unsigned short* slot = state_slot(st_lo, st_hi, bh, c);
#pragma unroll
  for (int i = 0; i < 2; ++i)
#pragma unroll
    for (int j = 0; j < 4; ++j)
#pragma unroll
      for (int r = 0; r < 4; ++r) {
        int p = wp * 32 + i * 16 + quad * 4 + r;
        int n = wn * 64 + j * 16 + c15;
        slot[p * 128 + n] = bf16_of(hacc[i][j][r]);
      }
}

// ---- SSD pass B: h_c = d_c*h_{c-1} + S_c; slot overwritten with h_{c-1}.
__global__ __launch_bounds__(256) void ssd_passB(const float* __restrict__ dtv,
                                                 const float* __restrict__ A_log,
                                                 unsigned short* __restrict__ st_lo,
                                                 unsigned short* __restrict__ st_hi) {
  const int bh = blockIdx.x >> 1;
  const int ph = blockIdx.x & 1;
  const int h = bh & 31;
  const int b = bh >> 5;
  const int tid = threadIdx.x;
  __shared__ float sd[NCHUNK];
  const float A = -__expf(A_log[h]);
  if (tid < NCHUNK) {
    float s = 0.f;
    const float* dp = dtv + (size_t)(b * L_ + tid * Q_) * NH + h;
    for (int i = 0; i < Q_; ++i) s += dp[(size_t)i * NH];
    sd[tid] = __expf(A * s);
  }
  __syncthreads();
  float hreg[16];
#pragma unroll
  for (int k = 0; k < 16; ++k) hreg[k] = 0.f;
  const size_t eoff = (size_t)ph * 4096 + (size_t)tid * 16;
  for (int c = 0; c < NCHUNK; ++c) {
    unsigned short* sp = state_slot(st_lo, st_hi, bh, c) + eoff;
    uint4 t0 = ((const uint4*)sp)[0];
    uint4 t1 = ((const uint4*)sp)[1];
    unsigned o[8];
#pragma unroll
    for (int k = 0; k < 8; ++k) o[k] = pk_bf16(hreg[2 * k], hreg[2 * k + 1]);
    ((uint4*)sp)[0] = make_uint4(o[0], o[1], o[2], o[3]);
    ((uint4*)sp)[1] = make_uint4(o[4], o[5], o[6], o[7]);
    float d = sd[c];
    const unsigned short* tv0 = (const unsigned short*)&t0;
    const unsigned short* tv1 = (const unsigned short*)&t1;
#pragma unroll
    for (int k = 0; k < 8; ++k) hreg[k] = d * hreg[k] + f_of_bf16(tv0[k]);
#pragma unroll
    for (int k = 0; k < 8; ++k) hreg[8 + k] = d * hreg[8 + k] + f_of_bf16(tv1[k]);
  }
}

// ---- SSD pass C: Y += exp(A*cs_t) * (C @ h_prev^T); RMW on xbc x-region.
__global__ __launch_bounds__(256) void ssd_passC(unsigned short* __restrict__ xbc,
                                                 const float* __restrict__ dtv,
                                                 const float* __restrict__ A_log,
                                                 const unsigned short* __restrict__ st_lo,
                                                 const unsigned short* __restrict__ st_hi) {
  const int bid = blockIdx.x;
  const int h = bid & 31;
  const int c = (bid >> 5) & 31;
  const int b = bid >> 10;
  const int bh = b * 32 + h;
  const int tid = threadIdx.x;
  const int w = tid >> 6;
  const int lane = tid & 63;
  const int quad = lane >> 4;
  const int c15 = lane & 15;

  __shared__ unsigned short sC[64 * 136];
  __shared__ unsigned short sH[64 * 136];
  __shared__ float srt[64];

  const float A = -__expf(A_log[h]);
  const int r0 = b * L_ + c * Q_;

  if (w == 0) {
    float v = dtv[(size_t)(r0 + lane) * NH + h];
    float s = v;
#pragma unroll
    for (int off = 1; off < 64; off <<= 1) {
      float t = __shfl_up(s, off, 64);
      if (lane >= off) s += t;
    }
    srt[lane] = __expf(A * s);
  }
  const unsigned short* slot =
      state_slot((unsigned short*)st_lo, (unsigned short*)st_hi, bh, c);
  for (int e = tid; e < 1024; e += 256) {
    int s = e >> 4, ch = e & 15;
    *(uint4*)&sC[s * 136 + ch * 8] =
        *(const uint4*)&xbc[(size_t)(r0 + s) * CONVDIM + DINNER + DSTATE + ch * 8];
    *(uint4*)&sH[s * 136 + ch * 8] = *(const uint4*)&slot[s * 128 + ch * 8];
  }
  __syncthreads();

  const int wt = w >> 1, wx = w & 1;
  f32x4 yacc[2][2];
#pragma unroll
  for (int i = 0; i < 2; ++i)
#pragma unroll
    for (int j = 0; j < 2; ++j) yacc[i][j] = f32x4{0.f, 0.f, 0.f, 0.f};
#pragma unroll
  for (int kk = 0; kk < 4; ++kk) {
    int k8 = quad * 8 + kk * 32;
    bf16x8 a0 = *(const bf16x8*)&sC[(wt * 32 + c15) * 136 + k8];
    bf16x8 a1 = *(const bf16x8*)&sC[(wt * 32 + 16 + c15) * 136 + k8];
    bf16x8 b0 = *(const bf16x8*)&sH[(wx * 32 + c15) * 136 + k8];
    bf16x8 b1 = *(const bf16x8*)&sH[(wx * 32 + 16 + c15) * 136 + k8];
    yacc[0][0] = __builtin_amdgcn_mfma_f32_16x16x32_bf16(a0, b0, yacc[0][0], 0, 0, 0);
    yacc[0][1] = __builtin_amdgcn_mfma_f32_16x16x32_bf16(a0, b1, yacc[0][1], 0, 0, 0);
    yacc[1][0] = __builtin_amdgcn_mfma_f32_16x16x32_bf16(a1, b0, yacc[1][0], 0, 0, 0);
    yacc[1][1] = __builtin_amdgcn_mfma_f32_16x16x32_bf16(a1, b1, yacc[1][1], 0, 0, 0);
  }
#pragma unroll
  for (int i = 0; i < 2; ++i)
#pragma unroll
    for (int j = 0; j < 2; ++j) {
      int p = wx * 32 + j * 16 + c15;
#pragma unroll
      for (int r = 0; r < 4; ++r) {
        int t = wt * 32 + i * 16 + quad * 4 + r;
        size_t ga = (size_t)(r0 + t) * CONVDIM + h * 64 + p;
        float v = yacc[i][j][r] * srt[t] + f_of_bf16(xbc[ga]);
        xbc[ga] = bf16_of(v);
      }
    }
}

// gate + RMSNorm; vectorized uint4 path (8 contiguous bf16 per thread).
__global__ __launch_bounds__(256) void norm_kernel(const unsigned short* __restrict__ y_in,
                                                   unsigned short* __restrict__ zxb,
                                                   const float* __restrict__ norm_w) {
  const int row = blockIdx.x;
  const int tid = threadIdx.x;
  const int c0 = tid * 8;
  uint4 yv4 = *(const uint4*)&y_in[(size_t)row * CONVDIM + c0];
  uint4 zv4 = *(const uint4*)&zxb[(size_t)row * DINPROJ + c0];
  const unsigned short* yv = (const unsigned short*)&yv4;
  const unsigned short* zv = (const unsigned short*)&zv4;
  float v[8];
  float ss = 0.f;
#pragma unroll
  for (int i = 0; i < 8; ++i) {
    float yf = f_of_bf16(yv[i]);
    float z = f_of_bf16(zv[i]);
    yf *= z / (1.f + __expf(-z));
    v[i] = yf;
    ss = fmaf(yf, yf, ss);
  }
#pragma unroll
  for (int o = 32; o > 0; o >>= 1) ss += __shfl_down(ss, o, 64);
  __shared__ float sred[4];
  if ((tid & 63) == 0) sred[tid >> 6] = ss;
  __syncthreads();
  float tot = (sred[0] + sred[1]) + (sred[2] + sred[3]);
  float r = rsqrtf(tot * (1.f / (float)DINNER) + 1e-5f);
  unsigned o4[4];
#pragma unroll
  for (int k = 0; k < 4; ++k)
    o4[k] = pk_bf16(v[2 * k] * r * norm_w[c0 + 2 * k],
                    v[2 * k + 1] * r * norm_w[c0 + 2 * k + 1]);
  *(uint4*)&zxb[(size_t)row * DINPROJ + c0] = make_uint4(o4[0], o4[1], o4[2], o4[3]);
}

extern "C" void kernel_launch(void* const* d_in, const int* in_sizes, int n_in,
                              void* d_out, int out_size, void* d_ws, size_t ws_size,
                              hipStream_t stream) {
  (void)in_sizes; (void)n_in; (void)out_size;
  const float* u          = (const float*)d_in[0];
  const float* in_proj_w  = (const float*)d_in[3];
  const float* conv_w     = (const float*)d_in[4];
  const float* conv_b     = (const float*)d_in[5];
  const float* dt_bias    = (const float*)d_in[6];
  const float* A_log      = (const float*)d_in[7];
  const float* Dvec       = (const float*)d_in[8];
  const float* norm_w     = (const float*)d_in[9];
  const float* out_proj_w = (const float*)d_in[10];
  float* out = (float*)d_out;

  constexpr size_t SZ_ZX   = (size_t)NROWS * DINPROJ * 2;   // 71,827,456
  constexpr size_t SZ_XBC  = (size_t)NROWS * CONVDIM * 2;   // 37,748,736
  constexpr size_t SZ_DT   = (size_t)NROWS * NH * 4;        //  1,048,576
  constexpr size_t SZ_SHR  = 33554432;                      // casts / states-hi
  constexpr size_t SZ_WOUT = (size_t)DMODEL * DINNER * 2;   //  4,194,304
  constexpr size_t NEED = SZ_ZX + SZ_XBC + SZ_DT + SZ_SHR + SZ_WOUT;  // 148,373,504
  if (ws_size < NEED) return;

  char* p = (char*)d_ws;
  unsigned short* zxb  = (unsigned short*)p; p += SZ_ZX;
  unsigned short* xbc  = (unsigned short*)p; p += SZ_XBC;
  float* dtv           = (float*)p;          p += SZ_DT;
  char* shared_reg     = p;                  p += SZ_SHR;
  unsigned short* wout_bf = (unsigned short*)p;

  unsigned short* u_bf   = (unsigned short*)shared_reg;
  unsigned short* win_bf = (unsigned short*)(shared_reg + 16777216);
  unsigned short* st_lo  = (unsigned short*)d_out;    // 2048 slots = 33.5MB exact
  unsigned short* st_hi  = (unsigned short*)shared_reg;

  cast4_kernel<<<(NROWS * DMODEL) / 1024, 256, 0, stream>>>(u, u_bf);
  cast4_kernel<<<(DINPROJ * DMODEL) / 1024, 256, 0, stream>>>(in_proj_w, win_bf);
  cast4_kernel<<<(DMODEL * DINNER) / 1024, 256, 0, stream>>>(out_proj_w, wout_bf);

  // GEMM1: M-tiles 64 (per_xcd 8), N-tiles 35 -> grid 2240
  gemm_lds_kernel<128, true><<<2240, 256, 0, stream>>>(
      u_bf, win_bf, zxb, NROWS, DINPROJ, DMODEL, DMODEL, DMODEL, DINPROJ, 8);
  conv_dt_kernel<<<dim3(9, NROWS), 256, 0, stream>>>(zxb, conv_w, conv_b, dt_bias,
                                                     xbc, dtv);

  ssd_passA<<<B_ * NCHUNK * NH, 256, 0, stream>>>(xbc, dtv, A_log, Dvec, st_lo, st_hi);
  ssd_passB<<<B_ * NH * 2, 256, 0, stream>>>(dtv, A_log, st_lo, st_hi);
  ssd_passC<<<B_ * NCHUNK * NH, 256, 0, stream>>>(xbc, dtv, A_log, st_lo, st_hi);

  norm_kernel<<<NROWS, 256, 0, stream>>>(xbc, zxb, norm_w);
  // GEMM2: MT=64 -> M-tiles 128 (per_xcd 16), N-tiles 8 -> grid 1024
  gemm_lds_kernel<64, false><<<1024, 256, 0, stream>>>(
      zxb, wout_bf, out, NROWS, DMODEL, DINNER, DINPROJ, DINNER, DMODEL, 16);
}